// Round 4
// baseline (4970.112 us; speedup 1.0000x reference)
//
#include <hip/hip_runtime.h>
#include <math.h>

#define HIDN 320
#define DIMN 64

// workspace float layout
#define W1T_OFF 0          // [64][320]   w1t[i][h'] = (M1*W1)[perm1[h'], i]
#define W2T_OFF 20480      // [320][320]  w2T[g'][h'] = (M2*W2)[perm2[g'], perm1[h']]
#define W3I_OFF 122880     // [64][320][2] interleaved {s-row i, t-row i+64} at perm2[g']
#define B1P_OFF 163840     // [320] b1[perm1]
#define B2P_OFF 164160     // [320] b2[perm2]
#define FTOT    164480
// workspace int layout (after floats): perm1[320] perm2[320] start1[65] start2[65]

__global__ __launch_bounds__(320) void maf_setup(const float* __restrict__ M1,
                                                 const float* __restrict__ M3,
                                                 int* __restrict__ wsi) {
  __shared__ int m0[HIDN], m1[HIDN];
  __shared__ int c1[64], c2[64];
  __shared__ int s1[65], s2[65];
  int t = threadIdx.x;
  if (t < 64) { c1[t] = 0; c2[t] = 0; }
  __syncthreads();
  if (t < HIDN) {
    float s = 0.f;
    for (int d = 0; d < DIMN; ++d) s += M1[t * DIMN + d];
    int a = (int)(s + 0.5f) - 1;          // m0 in [0,62]
    m0[t] = a;
    atomicAdd(&c1[a], 1);
    float sb = 0.f;
    for (int o = 0; o < DIMN; ++o) sb += M3[o * HIDN + t];
    int b = 63 - (int)(sb + 0.5f);        // m1 in [0,62]
    m1[t] = b;
    atomicAdd(&c2[b], 1);
  }
  __syncthreads();
  if (t == 0) {
    int a = 0;
    for (int v = 0; v < 64; ++v) { s1[v] = a; a += c1[v]; }
    s1[64] = a;
    a = 0;
    for (int v = 0; v < 64; ++v) { s2[v] = a; a += c2[v]; }
    s2[64] = a;
  }
  __syncthreads();
  if (t < HIDN) {
    int key = m0[t], rk = 0;
    for (int h = 0; h < t; ++h) rk += (m0[h] == key);
    wsi[s1[key] + rk] = t;                 // perm1
    int key2 = m1[t], rk2 = 0;
    for (int g = 0; g < t; ++g) rk2 += (m1[g] == key2);
    wsi[320 + s2[key2] + rk2] = t;         // perm2
  }
  if (t < 65) { wsi[640 + t] = s1[t]; wsi[705 + t] = s2[t]; }
}

__global__ void maf_fill(const float* __restrict__ W1, const float* __restrict__ b1,
                         const float* __restrict__ W2, const float* __restrict__ b2,
                         const float* __restrict__ W3,
                         const float* __restrict__ M1, const float* __restrict__ M2,
                         const float* __restrict__ M3,
                         const int* __restrict__ wsi, float* __restrict__ wsf) {
  int idx = blockIdx.x * blockDim.x + threadIdx.x;
  const int* p1 = wsi;
  const int* p2 = wsi + 320;
  if (idx < 20480) {                       // w1t[i][hp]
    int i = idx / 320, hp = idx % 320;
    int h = p1[hp];
    wsf[W1T_OFF + idx] = M1[h * 64 + i] * W1[h * 64 + i];
  } else if (idx < 122880) {               // w2T[gp][hp]
    int e = idx - 20480;
    int gp = e / 320, hp = e % 320;
    int h = p1[hp], g = p2[gp];
    wsf[idx] = M2[g * 320 + h] * W2[g * 320 + h];
  } else if (idx < 163840) {               // w3 interleaved: ((i*320+gp)*2 + c)
    int e = idx - 122880;
    int c = e & 1, q = e >> 1;
    int i = q / 320, gp = q % 320;
    int g = p2[gp];
    int row = i + (c ? 64 : 0);
    wsf[idx] = M3[row * 320 + g] * W3[row * 320 + g];
  } else if (idx < 164160) {
    wsf[idx] = b1[p1[idx - 163840]];
  } else if (idx < 164480) {
    wsf[idx] = b2[p2[idx - 164160]];
  }
}

#define RWS 16     // (b,t) rows per workgroup
#define H1S 328    // h1p LDS row stride (8 mod 32 -> 2-way bank aliasing = free)

__global__ __launch_bounds__(256, 4) void maf_main(
    const float* __restrict__ z, const float* __restrict__ b3,
    const float* __restrict__ wsf, const int* __restrict__ wsi,
    float* __restrict__ out) {
  __shared__ float h1p[RWS * H1S];
  __shared__ float zx[RWS * 64];           // z-reversed in, x out (in-place per step)
  __shared__ float b3s[128];
  __shared__ int s1s[65], s2s[65];

  const int tid = threadIdx.x;
  const int r = tid >> 4;    // row within block (0..15); 4 rows per wave
  const int j = tid & 15;    // lane within row-group
  const long long bt0 = (long long)blockIdx.x * RWS;

  const float* b1p = wsf + B1P_OFF;
  const float* b2p = wsf + B2P_OFF;
  float* h1r = h1p + r * H1S;

  // row-local h1 init (wave-local from here on)
  for (int c = j; c < HIDN; c += 16) h1r[c] = b1p[c];

  // load reversed z rows (cross-wave, coalesced)
  for (int k = tid; k < RWS * 64; k += 256) {
    int rr = k >> 6, c = k & 63;
    zx[k] = z[(bt0 + rr) * 64 + (63 - c)];
  }
  if (tid < 65) { s1s[tid] = wsi[640 + tid]; s2s[tid] = wsi[705 + tid]; }
  if (tid < 128) b3s[tid] = b3[tid];
  __syncthreads();           // the ONLY barrier

  // h2 pre-activations: register-resident, lane j owns g' = j + 16k
  float h2[20];
#pragma unroll
  for (int k = 0; k < 20; ++k) h2[k] = b2p[j + 16 * k];

  float logdet = 0.f;

  for (int i = 0; i < 64; ++i) {
    const int p   = __builtin_amdgcn_readfirstlane(s2s[i]);      // gather prefix end
    const int h0  = __builtin_amdgcn_readfirstlane(s1s[i]);      // finalize block
    const int h1e = __builtin_amdgcn_readfirstlane(s1s[i + 1]);

    // ---- gather s_i, t_i over ready layer-2 prefix (g' < p) ----
    // group-of-5 scalar guards: straight-line (load-batched) inside a group
    float ss = 0.f, tt = 0.f;
    const float* w3row = wsf + W3I_OFF + i * 640;
    const int keg = (p + 15) >> 4;         // k-blocks 0..keg-1 possibly active
#pragma unroll
    for (int grp = 0; grp < 4; ++grp) {
      if (grp * 5 < keg) {                 // wave-uniform group guard
#pragma unroll
        for (int kk = 0; kk < 5; ++kk) {
          const int k = grp * 5 + kk;
          const int g = j + 16 * k;
          float v = fmaxf(h2[k], 0.f);
          v = (g < p) ? v : 0.f;
          float2 w = *reinterpret_cast<const float2*>(w3row + 2 * g);
          ss = fmaf(w.x, v, ss);
          tt = fmaf(w.y, v, tt);
        }
      }
    }
#pragma unroll
    for (int m = 1; m < 16; m <<= 1) {     // butterfly within 16-lane row group
      ss += __shfl_xor(ss, m);
      tt += __shfl_xor(tt, m);
    }
    ss += b3s[i];
    tt += b3s[64 + i];
    const float xi = (zx[(r << 6) + i] - tt) * __expf(-ss);
    logdet -= ss;
    zx[(r << 6) + i] = xi;                 // all 16 lanes write same value

    // ---- finalize block(i) of layer-1, scatter into h2 regs (g' >= p) ----
    const float* w1row = wsf + W1T_OFF + i * HIDN;
    const int hb0 = h0 & ~7;               // 32B-aligned start
    const int k0 = p >> 4;                 // first possibly-active scatter block
    for (int hb = hb0; hb < h1e; hb += 8) {
      float av[8];
      {
        float4 ha = *reinterpret_cast<const float4*>(&h1r[hb]);
        float4 hb4 = *reinterpret_cast<const float4*>(&h1r[hb + 4]);
        float4 wa = *reinterpret_cast<const float4*>(w1row + hb);
        float4 wb = *reinterpret_cast<const float4*>(w1row + hb + 4);
        float hv[8] = {ha.x, ha.y, ha.z, ha.w, hb4.x, hb4.y, hb4.z, hb4.w};
        float wv[8] = {wa.x, wa.y, wa.z, wa.w, wb.x, wb.y, wb.z, wb.w};
#pragma unroll
        for (int u = 0; u < 8; ++u) {
          int hp = hb + u;
          float a = fmaf(wv[u], xi, hv[u]);
          av[u] = (hp >= h0 && hp < h1e) ? fmaxf(a, 0.f) : 0.f;
        }
      }
#pragma unroll
      for (int grp = 0; grp < 4; ++grp) {
        if (grp * 5 + 5 > k0) {            // group contains some k >= k0
#pragma unroll
          for (int kk = 0; kk < 5; ++kk) {
            const int k = grp * 5 + kk;
            const int g = j + 16 * k;
            const float* w2g = wsf + W2T_OFF + g * HIDN + hb;
            float4 qa = *reinterpret_cast<const float4*>(w2g);
            float4 qb = *reinterpret_cast<const float4*>(w2g + 4);
            float acc = h2[k];
            acc = fmaf(qa.x, av[0], acc);
            acc = fmaf(qa.y, av[1], acc);
            acc = fmaf(qa.z, av[2], acc);
            acc = fmaf(qa.w, av[3], acc);
            acc = fmaf(qb.x, av[4], acc);
            acc = fmaf(qb.y, av[5], acc);
            acc = fmaf(qb.z, av[6], acc);
            acc = fmaf(qb.w, av[7], acc);
            h2[k] = (g >= p) ? acc : h2[k];   // only suffix lanes keep update
          }
        }
      }
    }

    // ---- incremental layer-1 update for not-yet-final suffix (runtime loop) ----
    for (int hp = h1e + j; hp < HIDN; hp += 16) {
      h1r[hp] = fmaf(w1row[hp], xi, h1r[hp]);
    }
  }

  // ---- writeout (wave-local; no barrier needed) ----
#pragma unroll
  for (int u = 0; u < 4; ++u) {
    int c = j + 16 * u;
    float v = zx[(r << 6) + c];
    v = fminf(fmaxf(v, -100.f), 100.f);
    out[(bt0 + r) * 64 + c] = v;
  }
  if (j == 0) {
    float v = fminf(fmaxf(logdet, -100.f), 100.f);
    out[4194304LL + bt0 + r] = v;
  }
}

extern "C" void kernel_launch(void* const* d_in, const int* in_sizes, int n_in,
                              void* d_out, int out_size, void* d_ws, size_t ws_size,
                              hipStream_t stream) {
  const float* z  = (const float*)d_in[0];
  const float* W1 = (const float*)d_in[1];
  const float* b1 = (const float*)d_in[2];
  const float* W2 = (const float*)d_in[3];
  const float* b2 = (const float*)d_in[4];
  const float* W3 = (const float*)d_in[5];
  const float* b3 = (const float*)d_in[6];
  const float* M1 = (const float*)d_in[7];
  const float* M2 = (const float*)d_in[8];
  const float* M3 = (const float*)d_in[9];
  float* out = (float*)d_out;
  float* wsf = (float*)d_ws;
  int* wsi = (int*)((char*)d_ws + (size_t)FTOT * sizeof(float));

  if (ws_size < (size_t)FTOT * sizeof(float) + 770 * sizeof(int)) return;

  maf_setup<<<1, 320, 0, stream>>>(M1, M3, wsi);
  maf_fill<<<(164480 + 255) / 256, 256, 0, stream>>>(W1, b1, W2, b2, W3, M1, M2, M3, wsi, wsf);
  maf_main<<<4096, 256, 0, stream>>>(z, b3, wsf, wsi, out);
}

// Round 5
// 2349.184 us; speedup vs baseline: 2.1157x; 2.1157x over previous
//
#include <hip/hip_runtime.h>
#include <math.h>

#define HIDN 320
#define DIMN 64

// workspace float layout
#define W1T_OFF 0          // [64][320]   w1t[i][h'] = (M1*W1)[perm1[h'], i]
#define W2T_OFF 20480      // [320][320]  w2[h'][g'] = (M2*W2)[perm2[g'], perm1[h']]
#define W3I_OFF 122880     // [64][320][2] interleaved {s-row i, t-row i+64} at perm2[g']
#define B1P_OFF 163840     // [320] b1[perm1]
#define B2P_OFF 164160     // [320] b2[perm2]
#define FTOT    164480
// workspace int layout (after floats): perm1[320] perm2[320] start1[65] start2[65]

__global__ __launch_bounds__(320) void maf_setup(const float* __restrict__ M1,
                                                 const float* __restrict__ M3,
                                                 int* __restrict__ wsi) {
  __shared__ int m0[HIDN], m1[HIDN];
  __shared__ int c1[64], c2[64];
  __shared__ int s1[65], s2[65];
  int t = threadIdx.x;
  if (t < 64) { c1[t] = 0; c2[t] = 0; }
  __syncthreads();
  if (t < HIDN) {
    float s = 0.f;
    for (int d = 0; d < DIMN; ++d) s += M1[t * DIMN + d];
    int a = (int)(s + 0.5f) - 1;          // m0 in [0,62]
    m0[t] = a;
    atomicAdd(&c1[a], 1);
    float sb = 0.f;
    for (int o = 0; o < DIMN; ++o) sb += M3[o * HIDN + t];
    int b = 63 - (int)(sb + 0.5f);        // m1 in [0,62]
    m1[t] = b;
    atomicAdd(&c2[b], 1);
  }
  __syncthreads();
  if (t == 0) {
    int a = 0;
    for (int v = 0; v < 64; ++v) { s1[v] = a; a += c1[v]; }
    s1[64] = a;
    a = 0;
    for (int v = 0; v < 64; ++v) { s2[v] = a; a += c2[v]; }
    s2[64] = a;
  }
  __syncthreads();
  if (t < HIDN) {
    int key = m0[t], rk = 0;
    for (int h = 0; h < t; ++h) rk += (m0[h] == key);
    wsi[s1[key] + rk] = t;                 // perm1
    int key2 = m1[t], rk2 = 0;
    for (int g = 0; g < t; ++g) rk2 += (m1[g] == key2);
    wsi[320 + s2[key2] + rk2] = t;         // perm2
  }
  if (t < 65) { wsi[640 + t] = s1[t]; wsi[705 + t] = s2[t]; }
}

__global__ void maf_fill(const float* __restrict__ W1, const float* __restrict__ b1,
                         const float* __restrict__ W2, const float* __restrict__ b2,
                         const float* __restrict__ W3,
                         const float* __restrict__ M1, const float* __restrict__ M2,
                         const float* __restrict__ M3,
                         const int* __restrict__ wsi, float* __restrict__ wsf) {
  int idx = blockIdx.x * blockDim.x + threadIdx.x;
  const int* p1 = wsi;
  const int* p2 = wsi + 320;
  if (idx < 20480) {                       // w1t[i][hp]
    int i = idx / 320, hp = idx % 320;
    int h = p1[hp];
    wsf[W1T_OFF + idx] = M1[h * 64 + i] * W1[h * 64 + i];
  } else if (idx < 122880) {               // w2[hp][gp]  (round-1 layout)
    int e = idx - 20480;
    int hp = e / 320, gp = e % 320;
    int h = p1[hp], g = p2[gp];
    wsf[idx] = M2[g * 320 + h] * W2[g * 320 + h];
  } else if (idx < 163840) {               // w3 interleaved: ((i*320+gp)*2 + c)
    int e = idx - 122880;
    int c = e & 1, q = e >> 1;
    int i = q / 320, gp = q % 320;
    int g = p2[gp];
    int row = i + (c ? 64 : 0);
    wsf[idx] = M3[row * 320 + g] * W3[row * 320 + g];
  } else if (idx < 164160) {
    wsf[idx] = b1[p1[idx - 163840]];
  } else if (idx < 164480) {
    wsf[idx] = b2[p2[idx - 164160]];
  }
}

#define RWS 8      // (b,t) rows per workgroup (128 threads, 2 waves)
#define H1S 328    // h1p LDS row stride (8 mod 32 -> 2-way bank aliasing = free)

__global__ __launch_bounds__(128, 4) void maf_main(
    const float* __restrict__ z, const float* __restrict__ b3,
    const float* __restrict__ wsf, const int* __restrict__ wsi,
    float* __restrict__ out) {
  __shared__ float h1p[RWS * H1S];
  __shared__ float zx[RWS * 64];           // z-reversed in, x out (in-place per step)
  __shared__ float b3s[128];
  __shared__ int s1s[65];

  const int tid = threadIdx.x;
  const int r = tid >> 4;    // row within block (0..7); 4 rows per wave
  const int j = tid & 15;    // lane within row-group
  const long long bt0 = (long long)blockIdx.x * RWS;

  const float* b1p = wsf + B1P_OFF;
  const float* b2p = wsf + B2P_OFF;
  float* h1r = h1p + r * H1S;

  // row-local h1 init
  for (int c = j; c < HIDN; c += 16) h1r[c] = b1p[c];

  // load reversed z rows (coalesced)
  for (int k = tid; k < RWS * 64; k += 128) {
    int rr = k >> 6, c = k & 63;
    zx[k] = z[(bt0 + rr) * 64 + (63 - c)];
  }
  if (tid < 65) s1s[tid] = wsi[640 + tid];
  if (tid < 128) b3s[tid] = b3[tid];
  __syncthreads();

  // h2 pre-activations: register-resident, lane j owns g' = j + 16k
  float h2[20];
#pragma unroll
  for (int k = 0; k < 20; ++k) h2[k] = b2p[j + 16 * k];

  float logdet = 0.f;

  for (int i = 0; i < 64; ++i) {
    __syncthreads();   // keeps waves/blocks in lockstep -> shared per-step L1 slices

    // ---- gather s_i, t_i: dense, no guards (masked weights are exactly 0
    //      for non-ready g', so relu(partial h2)*0 == 0) ----
    float ss = 0.f, tt = 0.f;
    const float* w3row = wsf + W3I_OFF + i * 640;
#pragma unroll
    for (int k = 0; k < 20; ++k) {
      float v = fmaxf(h2[k], 0.f);
      float2 w = *reinterpret_cast<const float2*>(w3row + 2 * (j + 16 * k));
      ss = fmaf(w.x, v, ss);
      tt = fmaf(w.y, v, tt);
    }
#pragma unroll
    for (int m = 1; m < 16; m <<= 1) {     // butterfly within 16-lane row group
      ss += __shfl_xor(ss, m);
      tt += __shfl_xor(tt, m);
    }
    ss += b3s[i];
    tt += b3s[64 + i];
    const float xi = (zx[(r << 6) + i] - tt) * __expf(-ss);
    logdet -= ss;
    zx[(r << 6) + i] = xi;                 // all 16 lanes write same value

    // ---- finalize block(i) of layer-1, scatter into h2 regs.
    //      No per-lane g-guard: w2[h',g'] == 0 for finalized g'. Only the
    //      [h0,h1e) range mask on av is required (later blocks have nonzero
    //      weights but non-final h1 values). ----
    const int h0  = __builtin_amdgcn_readfirstlane(s1s[i]);
    const int h1e = __builtin_amdgcn_readfirstlane(s1s[i + 1]);
    const float* w1row = wsf + W1T_OFF + i * HIDN;
    for (int hb = h0 & ~7; hb < h1e; hb += 8) {
      float av[8];
      {
        float4 A  = *reinterpret_cast<const float4*>(&h1r[hb]);
        float4 Bv = *reinterpret_cast<const float4*>(&h1r[hb + 4]);
        float4 wa = *reinterpret_cast<const float4*>(w1row + hb);
        float4 wb = *reinterpret_cast<const float4*>(w1row + hb + 4);
        float hv[8] = {A.x, A.y, A.z, A.w, Bv.x, Bv.y, Bv.z, Bv.w};
        float wv[8] = {wa.x, wa.y, wa.z, wa.w, wb.x, wb.y, wb.z, wb.w};
#pragma unroll
        for (int u = 0; u < 8; ++u) {
          int hp = hb + u;
          float a = fmaf(wv[u], xi, hv[u]);
          av[u] = (hp >= h0 && hp < h1e) ? fmaxf(a, 0.f) : 0.f;
        }
      }
      const float* w2base = wsf + W2T_OFF + (size_t)hb * HIDN + j;
#pragma unroll
      for (int k = 0; k < 20; ++k) {
        const float* c0 = w2base + 16 * k;
        float acc = h2[k];
        acc = fmaf(c0[0 * HIDN], av[0], acc);
        acc = fmaf(c0[1 * HIDN], av[1], acc);
        acc = fmaf(c0[2 * HIDN], av[2], acc);
        acc = fmaf(c0[3 * HIDN], av[3], acc);
        acc = fmaf(c0[4 * HIDN], av[4], acc);
        acc = fmaf(c0[5 * HIDN], av[5], acc);
        acc = fmaf(c0[6 * HIDN], av[6], acc);
        acc = fmaf(c0[7 * HIDN], av[7], acc);
        h2[k] = acc;
      }
    }

    // ---- incremental layer-1 update for not-yet-final suffix ----
    for (int hp = h1e + j; hp < HIDN; hp += 16) {
      h1r[hp] = fmaf(w1row[hp], xi, h1r[hp]);
    }
  }

  // ---- writeout ----
#pragma unroll
  for (int u = 0; u < 4; ++u) {
    int c = j + 16 * u;
    float v = zx[(r << 6) + c];
    v = fminf(fmaxf(v, -100.f), 100.f);
    out[(bt0 + r) * 64 + c] = v;
  }
  if (j == 0) {
    float v = fminf(fmaxf(logdet, -100.f), 100.f);
    out[4194304LL + bt0 + r] = v;
  }
}

extern "C" void kernel_launch(void* const* d_in, const int* in_sizes, int n_in,
                              void* d_out, int out_size, void* d_ws, size_t ws_size,
                              hipStream_t stream) {
  const float* z  = (const float*)d_in[0];
  const float* W1 = (const float*)d_in[1];
  const float* b1 = (const float*)d_in[2];
  const float* W2 = (const float*)d_in[3];
  const float* b2 = (const float*)d_in[4];
  const float* W3 = (const float*)d_in[5];
  const float* b3 = (const float*)d_in[6];
  const float* M1 = (const float*)d_in[7];
  const float* M2 = (const float*)d_in[8];
  const float* M3 = (const float*)d_in[9];
  float* out = (float*)d_out;
  float* wsf = (float*)d_ws;
  int* wsi = (int*)((char*)d_ws + (size_t)FTOT * sizeof(float));

  if (ws_size < (size_t)FTOT * sizeof(float) + 770 * sizeof(int)) return;

  maf_setup<<<1, 320, 0, stream>>>(M1, M3, wsi);
  maf_fill<<<(164480 + 255) / 256, 256, 0, stream>>>(W1, b1, W2, b2, W3, M1, M2, M3, wsi, wsf);
  maf_main<<<8192, 128, 0, stream>>>(z, b3, wsf, wsi, out);
}

// Round 6
// 2253.096 us; speedup vs baseline: 2.2059x; 1.0426x over previous
//
#include <hip/hip_runtime.h>
#include <math.h>

#define HIDN 320
#define DIMN 64

// workspace float layout
#define W1T_OFF 0          // [64][320]    w1row[i][h'] = (M1*W1)[perm1[h'], i]
#define W2T_OFF 20480      // [20][40][16][8]  w2tile[gb][hc][j][u] = (M2*W2)[perm2[gb*16+j], perm1[hc*8+u]]
#define W3I_OFF 122880     // [64][16][40] w3tile[i][j][2k+c] = (M3*W3)[i+64c, perm2[16k+j]]
#define B1P_OFF 163840     // [320] b1[perm1]
#define B2P_OFF 164160     // [320] b2[perm2]
#define FTOT    164480
// workspace int layout (after floats): perm1[320] perm2[320] start1[65] start2[65]

__global__ __launch_bounds__(320) void maf_setup(const float* __restrict__ M1,
                                                 const float* __restrict__ M3,
                                                 int* __restrict__ wsi) {
  __shared__ int m0[HIDN], m1[HIDN];
  __shared__ int c1[64], c2[64];
  __shared__ int s1[65], s2[65];
  int t = threadIdx.x;
  if (t < 64) { c1[t] = 0; c2[t] = 0; }
  __syncthreads();
  if (t < HIDN) {
    float s = 0.f;
    for (int d = 0; d < DIMN; ++d) s += M1[t * DIMN + d];
    int a = (int)(s + 0.5f) - 1;          // m0 in [0,62]
    m0[t] = a;
    atomicAdd(&c1[a], 1);
    float sb = 0.f;
    for (int o = 0; o < DIMN; ++o) sb += M3[o * HIDN + t];
    int b = 63 - (int)(sb + 0.5f);        // m1 in [0,62]
    m1[t] = b;
    atomicAdd(&c2[b], 1);
  }
  __syncthreads();
  if (t == 0) {
    int a = 0;
    for (int v = 0; v < 64; ++v) { s1[v] = a; a += c1[v]; }
    s1[64] = a;
    a = 0;
    for (int v = 0; v < 64; ++v) { s2[v] = a; a += c2[v]; }
    s2[64] = a;
  }
  __syncthreads();
  if (t < HIDN) {
    int key = m0[t], rk = 0;
    for (int h = 0; h < t; ++h) rk += (m0[h] == key);
    wsi[s1[key] + rk] = t;                 // perm1
    int key2 = m1[t], rk2 = 0;
    for (int g = 0; g < t; ++g) rk2 += (m1[g] == key2);
    wsi[320 + s2[key2] + rk2] = t;         // perm2
  }
  if (t < 65) { wsi[640 + t] = s1[t]; wsi[705 + t] = s2[t]; }
}

__global__ void maf_fill(const float* __restrict__ W1, const float* __restrict__ b1,
                         const float* __restrict__ W2, const float* __restrict__ b2,
                         const float* __restrict__ W3,
                         const float* __restrict__ M1, const float* __restrict__ M2,
                         const float* __restrict__ M3,
                         const int* __restrict__ wsi, float* __restrict__ wsf) {
  int idx = blockIdx.x * blockDim.x + threadIdx.x;
  const int* p1 = wsi;
  const int* p2 = wsi + 320;
  if (idx < 20480) {                       // w1row[i][hp]
    int i = idx / 320, hp = idx % 320;
    int h = p1[hp];
    wsf[W1T_OFF + idx] = M1[h * 64 + i] * W1[h * 64 + i];
  } else if (idx < 122880) {               // w2tile[gb][hc][jj][u]
    int e = idx - 20480;
    int u = e & 7;
    int t1 = e >> 3;
    int jj = t1 & 15;
    int t2 = t1 >> 4;
    int hc = t2 % 40, gb = t2 / 40;
    int gp = gb * 16 + jj, hp = hc * 8 + u;
    int h = p1[hp], g = p2[gp];
    wsf[idx] = M2[g * HIDN + h] * W2[g * HIDN + h];
  } else if (idx < 163840) {               // w3tile[i][jj][2k+c]
    int e = idx - 122880;
    int c = e & 1;
    int k = (e % 40) >> 1;
    int jj = (e / 40) & 15;
    int i = e / 640;
    int gp = k * 16 + jj;
    int g = p2[gp];
    int row = i + (c ? 64 : 0);
    wsf[idx] = M3[row * HIDN + g] * W3[row * HIDN + g];
  } else if (idx < 164160) {
    wsf[idx] = b1[p1[idx - 163840]];
  } else if (idx < 164480) {
    wsf[idx] = b2[p2[idx - 164160]];
  }
}

#define RWS 16     // (b,t) rows per workgroup (256 threads, 4 waves)
#define H1S 328    // h1p LDS row stride (8 mod 32 -> 2-way bank aliasing = free)

__global__ __launch_bounds__(256, 4) void maf_main(
    const float* __restrict__ z, const float* __restrict__ b3,
    const float* __restrict__ wsf, const int* __restrict__ wsi,
    float* __restrict__ out) {
  __shared__ float h1p[RWS * H1S];
  __shared__ float zx[RWS * 64];           // z-reversed in, x out (in-place per step)
  __shared__ float b3s[128];
  __shared__ int s1s[65];

  const int tid = threadIdx.x;
  const int r = tid >> 4;    // row within block (0..15); 4 rows per wave
  const int j = tid & 15;    // lane within row-group
  const long long bt0 = (long long)blockIdx.x * RWS;

  float* h1r = h1p + r * H1S;

  // row-local h1 init
  for (int c = j; c < HIDN; c += 16) h1r[c] = wsf[B1P_OFF + c];

  // load reversed z rows (coalesced)
  for (int k = tid; k < RWS * 64; k += 256) {
    int rr = k >> 6, c = k & 63;
    zx[k] = z[(bt0 + rr) * 64 + (63 - c)];
  }
  if (tid < 65) s1s[tid] = wsi[640 + tid];
  if (tid < 128) b3s[tid] = b3[tid];
  __syncthreads();

  // h2 pre-activations: register-resident, lane j owns g' = j + 16k
  float h2[20];
#pragma unroll
  for (int k = 0; k < 20; ++k) h2[k] = wsf[B2P_OFF + j + 16 * k];

  float logdet = 0.f;

  for (int i = 0; i < 64; ++i) {
    __syncthreads();   // lockstep -> per-step weight slices shared in L1

    // ---- gather s_i, t_i: dense (masked weights are exactly 0 for
    //      non-ready g'), per-lane contiguous float4 loads, tree-summed ----
    const float* w3l = wsf + W3I_OFF + (i * 16 + j) * 40;
    float sa[4] = {0.f, 0.f, 0.f, 0.f};
    float ta[4] = {0.f, 0.f, 0.f, 0.f};
#pragma unroll
    for (int m = 0; m < 10; ++m) {
      float4 q = *reinterpret_cast<const float4*>(w3l + 4 * m);
      float v0 = fmaxf(h2[2 * m], 0.f);
      float v1 = fmaxf(h2[2 * m + 1], 0.f);
      sa[m & 3] = fmaf(q.x, v0, sa[m & 3]);
      ta[m & 3] = fmaf(q.y, v0, ta[m & 3]);
      sa[m & 3] = fmaf(q.z, v1, sa[m & 3]);
      ta[m & 3] = fmaf(q.w, v1, ta[m & 3]);
    }
    float ss = (sa[0] + sa[1]) + (sa[2] + sa[3]);
    float tt = (ta[0] + ta[1]) + (ta[2] + ta[3]);
#pragma unroll
    for (int m = 1; m < 16; m <<= 1) {     // butterfly within 16-lane row group
      ss += __shfl_xor(ss, m);
      tt += __shfl_xor(tt, m);
    }
    ss += b3s[i];
    tt += b3s[64 + i];
    const float xi = (zx[(r << 6) + i] - tt) * __expf(-ss);
    logdet -= ss;
    zx[(r << 6) + i] = xi;                 // all 16 lanes write same value

    // ---- finalize block(i) of layer-1, scatter into h2 regs.
    //      No per-lane g-guard needed (w2 == 0 for finalized g'); only the
    //      [h0,h1e) range mask on av is required. ----
    const int h0  = __builtin_amdgcn_readfirstlane(s1s[i]);
    const int h1e = __builtin_amdgcn_readfirstlane(s1s[i + 1]);
    const float* w1row = wsf + W1T_OFF + i * HIDN;
    for (int hb = h0 & ~7; hb < h1e; hb += 8) {
      float av[8];
      {
        float4 A  = *reinterpret_cast<const float4*>(&h1r[hb]);
        float4 Bv = *reinterpret_cast<const float4*>(&h1r[hb + 4]);
        float4 wa = *reinterpret_cast<const float4*>(w1row + hb);
        float4 wb = *reinterpret_cast<const float4*>(w1row + hb + 4);
        float hv[8] = {A.x, A.y, A.z, A.w, Bv.x, Bv.y, Bv.z, Bv.w};
        float wv[8] = {wa.x, wa.y, wa.z, wa.w, wb.x, wb.y, wb.z, wb.w};
#pragma unroll
        for (int u = 0; u < 8; ++u) {
          int hp = hb + u;
          float a = fmaf(wv[u], xi, hv[u]);
          av[u] = (hp >= h0 && hp < h1e) ? fmaxf(a, 0.f) : 0.f;
        }
      }
      // w2tile: lane j reads 8 contiguous floats per k-block (2x float4)
      const float* w2t = wsf + W2T_OFF + ((hb >> 3) * 16 + j) * 8;
#pragma unroll
      for (int k = 0; k < 20; ++k) {
        const float* c0 = w2t + k * 5120;   // gb stride = 40*16*8
        float4 qa = *reinterpret_cast<const float4*>(c0);
        float4 qb = *reinterpret_cast<const float4*>(c0 + 4);
        float acc = h2[k];
        acc = fmaf(qa.x, av[0], acc);
        acc = fmaf(qa.y, av[1], acc);
        acc = fmaf(qa.z, av[2], acc);
        acc = fmaf(qa.w, av[3], acc);
        acc = fmaf(qb.x, av[4], acc);
        acc = fmaf(qb.y, av[5], acc);
        acc = fmaf(qb.z, av[6], acc);
        acc = fmaf(qb.w, av[7], acc);
        h2[k] = acc;
      }
    }

    // ---- incremental layer-1 update for not-yet-final suffix ----
    for (int hp = h1e + j; hp < HIDN; hp += 16) {
      h1r[hp] = fmaf(w1row[hp], xi, h1r[hp]);
    }
  }

  // ---- writeout ----
#pragma unroll
  for (int u = 0; u < 4; ++u) {
    int c = j + 16 * u;
    float v = zx[(r << 6) + c];
    v = fminf(fmaxf(v, -100.f), 100.f);
    out[(bt0 + r) * 64 + c] = v;
  }
  if (j == 0) {
    float v = fminf(fmaxf(logdet, -100.f), 100.f);
    out[4194304LL + bt0 + r] = v;
  }
}

extern "C" void kernel_launch(void* const* d_in, const int* in_sizes, int n_in,
                              void* d_out, int out_size, void* d_ws, size_t ws_size,
                              hipStream_t stream) {
  const float* z  = (const float*)d_in[0];
  const float* W1 = (const float*)d_in[1];
  const float* b1 = (const float*)d_in[2];
  const float* W2 = (const float*)d_in[3];
  const float* b2 = (const float*)d_in[4];
  const float* W3 = (const float*)d_in[5];
  const float* b3 = (const float*)d_in[6];
  const float* M1 = (const float*)d_in[7];
  const float* M2 = (const float*)d_in[8];
  const float* M3 = (const float*)d_in[9];
  float* out = (float*)d_out;
  float* wsf = (float*)d_ws;
  int* wsi = (int*)((char*)d_ws + (size_t)FTOT * sizeof(float));

  if (ws_size < (size_t)FTOT * sizeof(float) + 770 * sizeof(int)) return;

  maf_setup<<<1, 320, 0, stream>>>(M1, M3, wsi);
  maf_fill<<<(164480 + 255) / 256, 256, 0, stream>>>(W1, b1, W2, b2, W3, M1, M2, M3, wsi, wsf);
  maf_main<<<4096, 256, 0, stream>>>(z, b3, wsf, wsi, out);
}